// Round 4
// baseline (432.670 us; speedup 1.0000x reference)
//
#include <hip/hip_runtime.h>
#include <hip/hip_bf16.h>

#define D_ 128
#define T_ 24
#define NPB 24576  /* rows per batch b in expert phase: T*H*W */

typedef __attribute__((ext_vector_type(8))) short bf16x8;
typedef __attribute__((ext_vector_type(4))) float f32x4;
typedef unsigned short ushortt;

static __device__ __forceinline__ void load8(const float* p, float* dst){
  float4 a = *(const float4*)p; float4 b = *(const float4*)(p+4);
  dst[0]=a.x;dst[1]=a.y;dst[2]=a.z;dst[3]=a.w;dst[4]=b.x;dst[5]=b.y;dst[6]=b.z;dst[7]=b.w;
}
static __device__ __forceinline__ bf16x8 cvt8(const float* f){
  union { bf16x8 v; __hip_bfloat162 h[4]; } u;
#pragma unroll
  for (int i=0;i<4;i++) u.h[i] = __float22bfloat162_rn(make_float2(f[2*i], f[2*i+1]));
  return u.v;
}
static __device__ __forceinline__ void split8(const float* f, bf16x8* hh, bf16x8* ll){
  union { bf16x8 v; __hip_bfloat162 h[4]; } uh, ul;
  float lo[8];
#pragma unroll
  for (int i=0;i<4;i++){
    __hip_bfloat162 p = __float22bfloat162_rn(make_float2(f[2*i], f[2*i+1]));
    uh.h[i] = p;
    lo[2*i]   = f[2*i]   - __bfloat162float(p.x);
    lo[2*i+1] = f[2*i+1] - __bfloat162float(p.y);
  }
#pragma unroll
  for (int i=0;i<4;i++) ul.h[i] = __float22bfloat162_rn(make_float2(lo[2*i], lo[2*i+1]));
  *hh = uh.v; *ll = ul.v;
}

// =====================================================================
// prep: pack weights into MFMA-fragment-linear layout.
// conv frags (hi/lo planes): wfC[l][tap][hl][fk][ng] -> 512-short frag,
//   element (n,k): lane = quad(k)*16 + (n&15), j = k&7.
// expert frags (bf16): wfE[e][fk][ng] (written only if do_e).
// =====================================================================
__global__ void prep_frags(const float* __restrict__ cw, const float* __restrict__ ew,
                           ushortt* __restrict__ wfC, ushortt* __restrict__ wfE, int do_e)
{
  const int idx = blockIdx.x*256 + threadIdx.x;
  if (idx < 10240){
    // conv item: (l, n, k8) : 5 x 128 x 16
    const int l  = idx >> 11;
    const int n  = (idx >> 4) & 127;
    const int k8 = (idx & 15) * 8;
    const float* src = cw + (size_t)((l*128 + n)*128 + k8)*4;   // [..][k][kh][kw] -> float4 = 4 taps
    float4 v[8];
#pragma unroll
    for (int kk=0;kk<8;++kk) v[kk] = *(const float4*)&src[kk*4];
    const int fk = k8>>5, q = (k8>>3)&3, ng = n>>4;
    const int lanoff = (q*16 + (n&15))*8;
#pragma unroll
    for (int tap=0; tap<4; ++tap){
      float f[8];
#pragma unroll
      for (int kk=0;kk<8;++kk) f[kk] = ((const float*)&v[kk])[tap];
      bf16x8 hh, ll; split8(f, &hh, &ll);
      const size_t baseH = (size_t)((((l*4+tap)*2+0)*4+fk)*8+ng)*512 + lanoff;
      const size_t baseL = (size_t)((((l*4+tap)*2+1)*4+fk)*8+ng)*512 + lanoff;
      *(bf16x8*)&wfC[baseH] = hh;
      *(bf16x8*)&wfC[baseL] = ll;
    }
  } else if (do_e && idx < 10240 + 14336){
    // expert item: (e, n, k8) : 7 x 128 x 16
    const int j  = idx - 10240;
    const int e  = j >> 11;
    const int n  = (j >> 4) & 127;
    const int k8 = (j & 15) * 8;
    float f[8];
#pragma unroll
    for (int kk=0;kk<8;++kk) f[kk] = ew[(size_t)(e*128 + k8+kk)*128 + n];
    const int fk = k8>>5, q = (k8>>3)&3, ng = n>>4;
    *(bf16x8*)&wfE[(size_t)((e*4+fk)*8+ng)*512 + (q*16 + (n&15))*8] = cvt8(f);
  }
}

// =====================================================================
// conv tile core: 128-row x 128-col output tile, K=128 per tap, 4 taps,
// split-bf16 (3 MFMA per term) => ~fp32 accuracy. LDS-free.
// =====================================================================
static __device__ __forceinline__ void conv_tile(
    const float* __restrict__ in, const ushortt* __restrict__ wf,
    int row0, int n_pix, int lw, f32x4 acc[4][4])
{
  const int t = threadIdx.x;
  const int w = t>>6, lane = t&63, quad = lane>>4, l16 = lane&15;
  const int mh = (w>>1)*64, nh = (w&1)*64;
  const int Wout = 1<<lw, Win = Wout<<1;
  int inb[4];
#pragma unroll
  for (int mg=0; mg<4; ++mg){
    int p = row0 + mh + mg*16 + l16;
    if (p > n_pix-1) p = n_pix-1;
    const int n   = p >> (2*lw);
    const int rem = p - (n << (2*lw));
    const int oy  = rem >> lw, ox = rem - (oy<<lw);
    inb[mg] = ((n*Win /*Hin*/ + 2*oy)*Win + 2*ox) << 7;
  }
#pragma unroll
  for (int mg=0;mg<4;++mg)
#pragma unroll
    for (int ngl=0;ngl<4;++ngl) acc[mg][ngl]=(f32x4){0.f,0.f,0.f,0.f};

  for (int tap=0; tap<4; ++tap){
    const int toff = (((tap>>1)*Win) + (tap&1)) << 7;
#pragma unroll
    for (int fk=0; fk<4; ++fk){
      bf16x8 ah[4], al[4];
#pragma unroll
      for (int mg=0; mg<4; ++mg){
        float f[8]; load8(in + inb[mg] + toff + fk*32 + quad*8, f);
        split8(f, &ah[mg], &al[mg]);
      }
#pragma unroll
      for (int ngl=0; ngl<4; ++ngl){
        const int ng = (nh>>4) + ngl;
        const bf16x8 bh = *(const bf16x8*)&wf[(size_t)(((tap*2+0)*4+fk)*8+ng)*512 + lane*8];
        const bf16x8 bl = *(const bf16x8*)&wf[(size_t)(((tap*2+1)*4+fk)*8+ng)*512 + lane*8];
#pragma unroll
        for (int mg=0; mg<4; ++mg){
          acc[mg][ngl] = __builtin_amdgcn_mfma_f32_16x16x32_bf16(ah[mg], bh, acc[mg][ngl], 0,0,0);
          acc[mg][ngl] = __builtin_amdgcn_mfma_f32_16x16x32_bf16(ah[mg], bl, acc[mg][ngl], 0,0,0);
          acc[mg][ngl] = __builtin_amdgcn_mfma_f32_16x16x32_bf16(al[mg], bh, acc[mg][ngl], 0,0,0);
        }
      }
    }
  }
}

__global__ __launch_bounds__(256)
void conv_mfma2(const float* __restrict__ in, float* __restrict__ out,
                const ushortt* __restrict__ wf,
                const float* __restrict__ cb,  const float* __restrict__ gam,
                const float* __restrict__ bet, const float* __restrict__ mn,
                const float* __restrict__ vr,  int n_pix, int lw)
{
  const int t = threadIdx.x;
  const int w = t>>6, lane = t&63, quad = lane>>4, l16 = lane&15;
  const int mh = (w>>1)*64, nh = (w&1)*64;
  const int row0 = blockIdx.x*128;
  f32x4 acc[4][4];
  conv_tile(in, wf, row0, n_pix, lw, acc);
#pragma unroll
  for (int ngl=0; ngl<4; ++ngl){
    const int col = nh + ngl*16 + l16;
    const float sc  = gam[col]*rsqrtf(vr[col]+1e-5f);
    const float cbv = cb[col], bt = bet[col], mv = mn[col];
#pragma unroll
    for (int mg=0; mg<4; ++mg)
#pragma unroll
      for (int r=0; r<4; ++r){
        const int pix = row0 + mh + mg*16 + quad*4 + r;
        if (pix < n_pix){
          float v = acc[mg][ngl][r] + cbv;
          v = sc*(v - mv) + bt;
          out[(size_t)pix*D_ + col] = v>0.f ? v : 0.2f*v;
        }
      }
  }
}

// =====================================================================
// fused conv-L4 (96 pixels) + gate: FFT + logits + top-2 softmax.
// Single block; z stays in LDS (stride 129 => conflict-free columns).
// =====================================================================
__global__ __launch_bounds__(256)
void conv_l4_gate(const float* __restrict__ in, const ushortt* __restrict__ wf,
                  const float* __restrict__ cb,  const float* __restrict__ gam,
                  const float* __restrict__ bet, const float* __restrict__ mn,
                  const float* __restrict__ vr,
                  const float* __restrict__ fw, const float* __restrict__ fb,
                  const float* __restrict__ wg, float* __restrict__ gbuf)
{
  __shared__ float zb[96*129];
  __shared__ float s[96];
  __shared__ float amp[4][12];
  __shared__ float logits[4][7];
  const int t = threadIdx.x;
  const int w = t>>6, lane = t&63, quad = lane>>4, l16 = lane&15;
  const int mh = (w>>1)*64, nh = (w&1)*64;
  f32x4 acc[4][4];
  conv_tile(in, wf, 0, 96, 0, acc);
#pragma unroll
  for (int ngl=0; ngl<4; ++ngl){
    const int col = nh + ngl*16 + l16;
    const float sc  = gam[col]*rsqrtf(vr[col]+1e-5f);
    const float cbv = cb[col], bt = bet[col], mv = mn[col];
#pragma unroll
    for (int mg=0; mg<4; ++mg)
#pragma unroll
      for (int r=0; r<4; ++r){
        const int pix = mh + mg*16 + quad*4 + r;
        if (pix < 96){
          float v = acc[mg][ngl][r] + cbv;
          v = sc*(v - mv) + bt;
          zb[pix*129 + col] = v>0.f ? v : 0.2f*v;
        }
      }
  }
  __syncthreads();
  if (t < 96){
    float a = 0.f;
    for (int d=0; d<D_; d++) a = fmaf(zb[t*129+d], fw[d], a);
    s[t] = a + fb[0];
  }
  __syncthreads();
  if (t < 48){
    const int b = t / 12, kf = (t % 12) + 1;
    float re=0.f, im=0.f;
    for (int tt=0; tt<T_; tt++){
      int ph = (kf*tt) % T_;
      float ang = (float)ph * (6.283185307179586f / (float)T_);
      re = fmaf(s[b*T_+tt], cosf(ang), re);
      im = fmaf(s[b*T_+tt], sinf(ang), im);
    }
    amp[b][t%12] = sqrtf(re*re + im*im) * 0.20412414523193150f; // ortho: 1/sqrt(24)
  }
  __syncthreads();
  if (t < 28){
    const int b = t/7, e = t - (t/7)*7;
    float a = 0.f;
    for (int k=0;k<12;k++) a = fmaf(amp[b][k], wg[k*7+e], a);
    logits[b][e] = a;
  }
  __syncthreads();
  if (t < 4){
    const int b = t;
    int i0=0; float v0=logits[b][0];
    for (int e=1;e<7;e++){ float v=logits[b][e]; if (v > v0){ v0=v; i0=e; } }
    int i1=-1; float v1=-3.4e38f;
    for (int e=0;e<7;e++){ if (e==i0) continue; float v=logits[b][e]; if (v > v1){ v1=v; i1=e; } }
    float ed = expf(v1 - v0);
    gbuf[b*4+0] = 1.f/(1.f+ed);
    gbuf[b*4+1] = ed/(1.f+ed);
    ((int*)gbuf)[b*4+2] = i0;
    ((int*)gbuf)[b*4+3] = i1;
  }
}

// =====================================================================
// expert: out = log(g0*exp(x@W_e0+b_e0) + g1*exp(x@W_e1+b_e1))
// WF=true : B-frags read directly from prepped global frags (no LDS, no barrier)
// WF=false: B-frags staged once into LDS frags (64 KB), one barrier
// =====================================================================
template<bool WF>
__global__ __launch_bounds__(256)
void expert2(const float* __restrict__ x, const float* __restrict__ ew,
             const ushortt* __restrict__ wfe, const float* __restrict__ eb,
             const float* __restrict__ gbuf, float* __restrict__ outp)
{
  __shared__ ushortt wlds[WF ? 16 : 32768];
  const int t = threadIdx.x;
  const int w = t>>6, lane = t&63, quad = lane>>4, l16 = lane&15;
  const int mh = (w>>1)*64, nh = (w&1)*64;
  const size_t row0 = (size_t)blockIdx.x * 128;
  const int b = (int)(row0 / NPB);
  const float g0 = gbuf[b*4+0], g1 = gbuf[b*4+1];
  const int e0 = ((const int*)gbuf)[b*4+2];
  const int e1 = ((const int*)gbuf)[b*4+3];

  if (!WF){
    const int el = t>>7, r7 = t&127;
    const int n0 = (r7&31)*4, k0 = (r7>>5)*16;
    const int esel = el ? e1 : e0;
#pragma unroll
    for (int h=0; h<2; ++h)
#pragma unroll
      for (int sub=0; sub<2; ++sub){
        const int kb = h*64 + k0 + sub*8;
        float4 v[8];
#pragma unroll
        for (int kk=0;kk<8;++kk)
          v[kk] = *(const float4*)&ew[(size_t)esel*16384 + (size_t)(kb+kk)*D_ + n0];
        const int fk = kb>>5, q = (kb>>3)&3;
#pragma unroll
        for (int n=0;n<4;++n){
          float f[8];
#pragma unroll
          for (int kk=0;kk<8;++kk) f[kk] = ((const float*)&v[kk])[n];
          *(bf16x8*)&wlds[(size_t)(((el*4+fk)*8 + ((n0+n)>>4))*512 + (q*16 + ((n0+n)&15))*8)] = cvt8(f);
        }
      }
    __syncthreads();
  }

  f32x4 acc[2][4][4];
#pragma unroll
  for (int e=0;e<2;++e)
#pragma unroll
    for (int mg=0;mg<4;++mg)
#pragma unroll
      for (int ngl=0;ngl<4;++ngl) acc[e][mg][ngl]=(f32x4){0.f,0.f,0.f,0.f};

#pragma unroll
  for (int fk=0; fk<4; ++fk){
    bf16x8 a[4];
#pragma unroll
    for (int mg=0; mg<4; ++mg){
      float f[8]; load8(x + (row0 + mh + mg*16 + l16)*D_ + fk*32 + quad*8, f);
      a[mg] = cvt8(f);
    }
#pragma unroll
    for (int e=0; e<2; ++e){
      const int eg = e ? e1 : e0;
#pragma unroll
      for (int ngl=0; ngl<4; ++ngl){
        const int ng = (nh>>4) + ngl;
        bf16x8 bb;
        if (WF) bb = *(const bf16x8*)&wfe[(size_t)((eg*4+fk)*8+ng)*512 + lane*8];
        else    bb = *(const bf16x8*)&wlds[(size_t)((e*4+fk)*8+ng)*512 + lane*8];
#pragma unroll
        for (int mg=0; mg<4; ++mg)
          acc[e][mg][ngl] = __builtin_amdgcn_mfma_f32_16x16x32_bf16(a[mg], bb, acc[e][mg][ngl], 0,0,0);
      }
    }
  }
#pragma unroll
  for (int ngl=0; ngl<4; ++ngl){
    const int col = nh + ngl*16 + l16;
    const float be0 = eb[e0*D_ + col];
    const float be1 = eb[e1*D_ + col];
#pragma unroll
    for (int mg=0; mg<4; ++mg)
#pragma unroll
      for (int r=0; r<4; ++r){
        const size_t row = row0 + mh + mg*16 + quad*4 + r;
        float c = g0*__expf(acc[0][mg][ngl][r] + be0) + g1*__expf(acc[1][mg][ngl][r] + be1);
        if (c == 0.f) c = 2.220446049250313e-16f;
        outp[row*D_ + col] = __logf(c);
      }
  }
}

extern "C" void kernel_launch(void* const* d_in, const int* in_sizes, int n_in,
                              void* d_out, int out_size, void* d_ws, size_t ws_size,
                              hipStream_t stream)
{
  const float* x   = (const float*)d_in[0];
  const float* cw  = (const float*)d_in[1];
  const float* cb  = (const float*)d_in[2];
  const float* gam = (const float*)d_in[3];
  const float* bet = (const float*)d_in[4];
  const float* mn  = (const float*)d_in[5];
  const float* vr  = (const float*)d_in[6];
  const float* fw  = (const float*)d_in[7];
  const float* fb  = (const float*)d_in[8];
  const float* wg  = (const float*)d_in[9];
  const float* ew  = (const float*)d_in[10];
  const float* eb  = (const float*)d_in[11];
  float* out = (float*)d_out;

  // Scratch inside d_out (50.3 MB), fully overwritten by expert2 at the end:
  //   wfC  [0,        1310720)  conv weight frags (hi/lo bf16)
  //   bufA [1310720, 13893632)  pixel buffers (L0/L2 out)
  //   bufB [13893632,17039360)  (L1/L3 out)
  char* sb = (char*)d_out;
  ushortt* wfC = (ushortt*)sb;
  float* bufA  = (float*)(sb + 1310720);
  float* bufB  = (float*)(sb + 13893632);
  float* gbuf  = (float*)d_ws;                 // 64 B, survives out overwrite

  const bool use_wf = ws_size >= (size_t)(64 + 7*4*8*512*2);
  ushortt* wfE = use_wf ? (ushortt*)((char*)d_ws + 64) : wfC /*dummy, unwritten*/;

  prep_frags<<<96, 256, 0, stream>>>(cw, ew, wfC, wfE, use_wf ? 1 : 0);
  conv_mfma2<<<192, 256, 0, stream>>>(x,    bufA, wfC,          cb,     gam,     bet,     mn,     vr,     24576, 4);
  conv_mfma2<<< 48, 256, 0, stream>>>(bufA, bufB, wfC + 131072, cb+128, gam+128, bet+128, mn+128, vr+128,  6144, 3);
  conv_mfma2<<< 12, 256, 0, stream>>>(bufB, bufA, wfC + 262144, cb+256, gam+256, bet+256, mn+256, vr+256,  1536, 2);
  conv_mfma2<<<  3, 256, 0, stream>>>(bufA, bufB, wfC + 393216, cb+384, gam+384, bet+384, mn+384, vr+384,   384, 1);
  conv_l4_gate<<<1, 256, 0, stream>>>(bufB, wfC + 524288, cb+512, gam+512, bet+512, mn+512, vr+512, fw, fb, wg, gbuf);
  if (use_wf) expert2<true ><<<768, 256, 0, stream>>>(x, ew, wfE, eb, gbuf, out);
  else        expert2<false><<<768, 256, 0, stream>>>(x, ew, wfE, eb, gbuf, out);
}

// Round 5
// 221.160 us; speedup vs baseline: 1.9564x; 1.9564x over previous
//
#include <hip/hip_runtime.h>
#include <hip/hip_bf16.h>

#define D_ 128
#define T_ 24
#define NPB 24576  /* rows per batch b in expert phase: T*H*W */

typedef __attribute__((ext_vector_type(8))) short bf16x8;
typedef __attribute__((ext_vector_type(4))) float f32x4;
typedef unsigned short ushortt;

static __device__ __forceinline__ void load8(const float* p, float* dst){
  float4 a = *(const float4*)p; float4 b = *(const float4*)(p+4);
  dst[0]=a.x;dst[1]=a.y;dst[2]=a.z;dst[3]=a.w;dst[4]=b.x;dst[5]=b.y;dst[6]=b.z;dst[7]=b.w;
}
static __device__ __forceinline__ bf16x8 cvt8(const float* f){
  union { bf16x8 v; __hip_bfloat162 h[4]; } u;
#pragma unroll
  for (int i=0;i<4;i++) u.h[i] = __float22bfloat162_rn(make_float2(f[2*i], f[2*i+1]));
  return u.v;
}
static __device__ __forceinline__ void split8(const float* f, bf16x8* hh, bf16x8* ll){
  union { bf16x8 v; __hip_bfloat162 h[4]; } uh, ul;
  float lo[8];
#pragma unroll
  for (int i=0;i<4;i++){
    __hip_bfloat162 p = __float22bfloat162_rn(make_float2(f[2*i], f[2*i+1]));
    uh.h[i] = p;
    lo[2*i]   = f[2*i]   - __bfloat162float(p.x);
    lo[2*i+1] = f[2*i+1] - __bfloat162float(p.y);
  }
#pragma unroll
  for (int i=0;i<4;i++) ul.h[i] = __float22bfloat162_rn(make_float2(lo[2*i], lo[2*i+1]));
  *hh = uh.v; *ll = ul.v;
}

// =====================================================================
// prep: pack weights into MFMA-fragment-linear layout (verified R4).
// conv frags (hi/lo planes): wfC[l][tap][hl][fk][ng] -> 512-short frag,
//   element (n,k): lane = quad(k)*16 + (n&15), j = k&7.
// expert frags (bf16): wfE[e][fk][ng] (written only if do_e).
// =====================================================================
__global__ void prep_frags(const float* __restrict__ cw, const float* __restrict__ ew,
                           ushortt* __restrict__ wfC, ushortt* __restrict__ wfE, int do_e)
{
  const int idx = blockIdx.x*256 + threadIdx.x;
  if (idx < 10240){
    const int l  = idx >> 11;
    const int n  = (idx >> 4) & 127;
    const int k8 = (idx & 15) * 8;
    const float* src = cw + (size_t)((l*128 + n)*128 + k8)*4;   // float4 = 4 taps
    float4 v[8];
#pragma unroll
    for (int kk=0;kk<8;++kk) v[kk] = *(const float4*)&src[kk*4];
    const int fk = k8>>5, q = (k8>>3)&3, ng = n>>4;
    const int lanoff = (q*16 + (n&15))*8;
#pragma unroll
    for (int tap=0; tap<4; ++tap){
      float f[8];
#pragma unroll
      for (int kk=0;kk<8;++kk) f[kk] = ((const float*)&v[kk])[tap];
      bf16x8 hh, ll; split8(f, &hh, &ll);
      *(bf16x8*)&wfC[(size_t)((((l*4+tap)*2+0)*4+fk)*8+ng)*512 + lanoff] = hh;
      *(bf16x8*)&wfC[(size_t)((((l*4+tap)*2+1)*4+fk)*8+ng)*512 + lanoff] = ll;
    }
  } else if (do_e && idx < 10240 + 14336){
    const int j  = idx - 10240;
    const int e  = j >> 11;
    const int n  = (j >> 4) & 127;
    const int k8 = (j & 15) * 8;
    float f[8];
#pragma unroll
    for (int kk=0;kk<8;++kk) f[kk] = ew[(size_t)(e*128 + k8+kk)*128 + n];
    const int fk = k8>>5, q = (k8>>3)&3, ng = n>>4;
    *(bf16x8*)&wfE[(size_t)((e*4+fk)*8+ng)*512 + (q*16 + (n&15))*8] = cvt8(f);
  }
}

// =====================================================================
// conv layer, MG*16 rows x 128 cols per block, 4 waves each MG*16 x 32.
// split-bf16 (3 MFMA/term) => ~fp32 accuracy. LDS-free, grid-exact.
// =====================================================================
template<int MG>
__global__ __launch_bounds__(256, 4)
void conv3(const float* __restrict__ in, float* __restrict__ out,
           const ushortt* __restrict__ wf,
           const float* __restrict__ cb,  const float* __restrict__ gam,
           const float* __restrict__ bet, const float* __restrict__ mn,
           const float* __restrict__ vr,  int n_pix, int lw)
{
  const int t = threadIdx.x;
  const int w = t>>6, lane = t&63, quad = lane>>4, l16 = lane&15;
  const int nh = w*32;
  const int row0 = blockIdx.x*(MG*16);
  const int Win = 2<<lw;
  int inb[MG];
#pragma unroll
  for (int mg=0; mg<MG; ++mg){
    const int p = row0 + mg*16 + l16;
    const int n   = p >> (2*lw);
    const int rem = p - (n << (2*lw));
    const int oy  = rem >> lw, ox = rem - (oy<<lw);
    inb[mg] = ((n*Win /*Hin==Win*/ + 2*oy)*Win + 2*ox) << 7;
  }
  f32x4 acc[MG][2];
#pragma unroll
  for (int mg=0;mg<MG;++mg){ acc[mg][0]=(f32x4){0,0,0,0}; acc[mg][1]=acc[mg][0]; }

#pragma unroll
  for (int tap=0; tap<4; ++tap){
    const int toff = (((tap>>1)*Win) + (tap&1)) << 7;
#pragma unroll
    for (int fk=0; fk<4; ++fk){
      bf16x8 ah[MG], al[MG];
#pragma unroll
      for (int mg=0; mg<MG; ++mg){
        float f[8]; load8(in + inb[mg] + toff + fk*32 + quad*8, f);
        split8(f, &ah[mg], &al[mg]);
      }
#pragma unroll
      for (int ngl=0; ngl<2; ++ngl){
        const int ng = w*2 + ngl;
        const bf16x8 bh = *(const bf16x8*)&wf[(size_t)(((tap*2+0)*4+fk)*8+ng)*512 + lane*8];
        const bf16x8 bl = *(const bf16x8*)&wf[(size_t)(((tap*2+1)*4+fk)*8+ng)*512 + lane*8];
#pragma unroll
        for (int mg=0; mg<MG; ++mg){
          acc[mg][ngl] = __builtin_amdgcn_mfma_f32_16x16x32_bf16(ah[mg], bh, acc[mg][ngl], 0,0,0);
          acc[mg][ngl] = __builtin_amdgcn_mfma_f32_16x16x32_bf16(ah[mg], bl, acc[mg][ngl], 0,0,0);
          acc[mg][ngl] = __builtin_amdgcn_mfma_f32_16x16x32_bf16(al[mg], bh, acc[mg][ngl], 0,0,0);
        }
      }
    }
  }
#pragma unroll
  for (int ngl=0; ngl<2; ++ngl){
    const int col = nh + ngl*16 + l16;
    const float sc  = gam[col]*rsqrtf(vr[col]+1e-5f);
    const float cbv = cb[col], bt = bet[col], mv = mn[col];
#pragma unroll
    for (int mg=0; mg<MG; ++mg)
#pragma unroll
      for (int r=0; r<4; ++r){
        const int pix = row0 + mg*16 + quad*4 + r;
        float v = acc[mg][ngl][r] + cbv;
        v = sc*(v - mv) + bt;
        out[(size_t)pix*D_ + col] = v>0.f ? v : 0.2f*v;
      }
  }
}

// ---- standalone gate: fuse dot + rFFT(1..12) + logits + top-2 softmax ----
__global__ void gate_kernel(const float* __restrict__ z, const float* __restrict__ fw,
                            const float* __restrict__ fb, const float* __restrict__ wg,
                            float* __restrict__ gbuf)
{
  __shared__ float s[96];
  __shared__ float amp[4][12];
  __shared__ float logits[4][7];
  const int t = threadIdx.x;
  if (t < 96){
    float a = 0.f;
    for (int d=0; d<D_; d++) a = fmaf(z[t*D_+d], fw[d], a);
    s[t] = a + fb[0];
  }
  __syncthreads();
  if (t < 48){
    const int b = t / 12, kf = (t % 12) + 1;
    float re=0.f, im=0.f;
    for (int tt=0; tt<T_; tt++){
      int ph = (kf*tt) % T_;
      float ang = (float)ph * (6.283185307179586f / (float)T_);
      re = fmaf(s[b*T_+tt], cosf(ang), re);
      im = fmaf(s[b*T_+tt], sinf(ang), im);
    }
    amp[b][t%12] = sqrtf(re*re + im*im) * 0.20412414523193150f; // ortho: 1/sqrt(24)
  }
  __syncthreads();
  if (t < 28){
    const int b = t/7, e = t - (t/7)*7;
    float a = 0.f;
    for (int k=0;k<12;k++) a = fmaf(amp[b][k], wg[k*7+e], a);
    logits[b][e] = a;
  }
  __syncthreads();
  if (t < 4){
    const int b = t;
    int i0=0; float v0=logits[b][0];
    for (int e=1;e<7;e++){ float v=logits[b][e]; if (v > v0){ v0=v; i0=e; } }
    int i1=-1; float v1=-3.4e38f;
    for (int e=0;e<7;e++){ if (e==i0) continue; float v=logits[b][e]; if (v > v1){ v1=v; i1=e; } }
    float ed = expf(v1 - v0);
    gbuf[b*4+0] = 1.f/(1.f+ed);
    gbuf[b*4+1] = ed/(1.f+ed);
    ((int*)gbuf)[b*4+2] = i0;
    ((int*)gbuf)[b*4+3] = i1;
  }
}

// =====================================================================
// expert: out = log(g0*exp(x@W_e0+b_e0) + g1*exp(x@W_e1+b_e1))
// 64 rows x 128 cols per block (1536 blocks); wave = 64r x 32c x 2 experts.
// =====================================================================
template<bool WF>
__global__ __launch_bounds__(256, 3)
void expert3(const float* __restrict__ x, const float* __restrict__ ew,
             const ushortt* __restrict__ wfe, const float* __restrict__ eb,
             const float* __restrict__ gbuf, float* __restrict__ outp)
{
  __shared__ ushortt wlds[WF ? 16 : 32768];
  const int t = threadIdx.x;
  const int w = t>>6, lane = t&63, quad = lane>>4, l16 = lane&15;
  const int nh = w*32;
  const size_t row0 = (size_t)blockIdx.x * 64;
  const int b = (int)(row0 / NPB);
  const float g0 = gbuf[b*4+0], g1 = gbuf[b*4+1];
  const int e0 = ((const int*)gbuf)[b*4+2];
  const int e1 = ((const int*)gbuf)[b*4+3];

  if (!WF){
    const int el = t>>7, r7 = t&127;
    const int n0 = (r7&31)*4, k0 = (r7>>5)*16;
    const int esel = el ? e1 : e0;
#pragma unroll
    for (int h=0; h<2; ++h)
#pragma unroll
      for (int sub=0; sub<2; ++sub){
        const int kb = h*64 + k0 + sub*8;
        float4 v[8];
#pragma unroll
        for (int kk=0;kk<8;++kk)
          v[kk] = *(const float4*)&ew[(size_t)esel*16384 + (size_t)(kb+kk)*D_ + n0];
        const int fk = kb>>5, q = (kb>>3)&3;
#pragma unroll
        for (int n=0;n<4;++n){
          float f[8];
#pragma unroll
          for (int kk=0;kk<8;++kk) f[kk] = ((const float*)&v[kk])[n];
          *(bf16x8*)&wlds[(size_t)(((el*4+fk)*8 + ((n0+n)>>4))*512 + (q*16 + ((n0+n)&15))*8)] = cvt8(f);
        }
      }
    __syncthreads();
  }

  f32x4 acc[2][4][2];
#pragma unroll
  for (int e=0;e<2;++e)
#pragma unroll
    for (int mg=0;mg<4;++mg){ acc[e][mg][0]=(f32x4){0,0,0,0}; acc[e][mg][1]=acc[e][mg][0]; }

#pragma unroll
  for (int fk=0; fk<4; ++fk){
    bf16x8 a[4];
#pragma unroll
    for (int mg=0; mg<4; ++mg){
      float f[8]; load8(x + (row0 + mg*16 + l16)*D_ + fk*32 + quad*8, f);
      a[mg] = cvt8(f);
    }
#pragma unroll
    for (int e=0; e<2; ++e){
      const int eg = e ? e1 : e0;
#pragma unroll
      for (int ngl=0; ngl<2; ++ngl){
        const int ng = w*2 + ngl;
        bf16x8 bb;
        if (WF) bb = *(const bf16x8*)&wfe[(size_t)((eg*4+fk)*8+ng)*512 + lane*8];
        else    bb = *(const bf16x8*)&wlds[(size_t)((e*4+fk)*8+ng)*512 + lane*8];
#pragma unroll
        for (int mg=0; mg<4; ++mg)
          acc[e][mg][ngl] = __builtin_amdgcn_mfma_f32_16x16x32_bf16(a[mg], bb, acc[e][mg][ngl], 0,0,0);
      }
    }
  }
#pragma unroll
  for (int ngl=0; ngl<2; ++ngl){
    const int col = nh + ngl*16 + l16;
    const float be0 = eb[e0*D_ + col];
    const float be1 = eb[e1*D_ + col];
#pragma unroll
    for (int mg=0; mg<4; ++mg)
#pragma unroll
      for (int r=0; r<4; ++r){
        const size_t row = row0 + mg*16 + quad*4 + r;
        float c = g0*__expf(acc[0][mg][ngl][r] + be0) + g1*__expf(acc[1][mg][ngl][r] + be1);
        if (c == 0.f) c = 2.220446049250313e-16f;
        outp[row*D_ + col] = __logf(c);
      }
  }
}

extern "C" void kernel_launch(void* const* d_in, const int* in_sizes, int n_in,
                              void* d_out, int out_size, void* d_ws, size_t ws_size,
                              hipStream_t stream)
{
  const float* x   = (const float*)d_in[0];
  const float* cw  = (const float*)d_in[1];
  const float* cb  = (const float*)d_in[2];
  const float* gam = (const float*)d_in[3];
  const float* bet = (const float*)d_in[4];
  const float* mn  = (const float*)d_in[5];
  const float* vr  = (const float*)d_in[6];
  const float* fw  = (const float*)d_in[7];
  const float* fb  = (const float*)d_in[8];
  const float* wg  = (const float*)d_in[9];
  const float* ew  = (const float*)d_in[10];
  const float* eb  = (const float*)d_in[11];
  float* out = (float*)d_out;

  // Scratch inside d_out (50.3 MB), fully overwritten by expert3 at the end:
  //   wfC  [0,        1310720)   conv weight frags (hi/lo bf16)
  //   bufA [1310720,  13893632)  pixel buffers (L0/L2 out)
  //   bufB [13893632, 17039360)  (L1/L3 out)
  //   zbuf [17039360, 17088512)  (L4 out, 96x128 fp32)
  char* sb = (char*)d_out;
  ushortt* wfC = (ushortt*)sb;
  float* bufA  = (float*)(sb + 1310720);
  float* bufB  = (float*)(sb + 13893632);
  float* zbuf  = (float*)(sb + 17039360);
  float* gbuf  = (float*)d_ws;                 // 64 B, survives out overwrite

  const bool use_wf = ws_size >= (size_t)(64 + 7*4*8*512*2);
  ushortt* wfE = use_wf ? (ushortt*)((char*)d_ws + 64) : wfC /*dummy, unwritten*/;

  prep_frags<<<96, 256, 0, stream>>>(cw, ew, wfC, wfE, use_wf ? 1 : 0);
  conv3<2><<<768, 256, 0, stream>>>(x,    bufA, wfC,          cb,     gam,     bet,     mn,     vr,     24576, 4);
  conv3<2><<<192, 256, 0, stream>>>(bufA, bufB, wfC + 131072, cb+128, gam+128, bet+128, mn+128, vr+128,  6144, 3);
  conv3<1><<< 96, 256, 0, stream>>>(bufB, bufA, wfC + 262144, cb+256, gam+256, bet+256, mn+256, vr+256,  1536, 2);
  conv3<1><<< 24, 256, 0, stream>>>(bufA, bufB, wfC + 393216, cb+384, gam+384, bet+384, mn+384, vr+384,   384, 1);
  conv3<1><<<  6, 256, 0, stream>>>(bufB, zbuf, wfC + 524288, cb+512, gam+512, bet+512, mn+512, vr+512,    96, 0);
  gate_kernel<<<1, 128, 0, stream>>>(zbuf, fw, fb, wg, gbuf);
  if (use_wf) expert3<true ><<<1536, 256, 0, stream>>>(x, ew, wfE, eb, gbuf, out);
  else        expert3<false><<<1536, 256, 0, stream>>>(x, ew, wfE, eb, gbuf, out);
}